// Round 1
// baseline (521.773 us; speedup 1.0000x reference)
//
#include <hip/hip_runtime.h>
#include <stdint.h>

// Problem dims
#define BB 8
#define SS 1024
#define DD 1024
#define HH 16
#define DFF 4096
#define MT (BB*SS)   // 8192 tokens

typedef __attribute__((ext_vector_type(8))) short bf16x8;  // 8 bf16 in 4 VGPRs
typedef __attribute__((ext_vector_type(4))) short s16x4;
typedef __attribute__((ext_vector_type(4))) float f32x4;

__device__ __forceinline__ short f2bf(float f) {
  union { float f; uint32_t u; } v; v.f = f;
  uint32_t r = v.u + 0x7FFFu + ((v.u >> 16) & 1u);   // RNE
  return (short)(r >> 16);
}

// async global->LDS, 16B per lane. LDS dest must be wave-uniform base (+lane*16 implicit).
__device__ __forceinline__ void gload_lds16(const void* g, void* l) {
  __builtin_amdgcn_global_load_lds(
      (__attribute__((address_space(1))) uint32_t*)(uintptr_t)g,
      (__attribute__((address_space(3))) uint32_t*)(uint32_t)(uintptr_t)l,
      16, 0, 0);
}

// ---------------- fp32 -> bf16 convert ----------------
__global__ __launch_bounds__(256) void cvt_bf16(const float* __restrict__ in,
                                                short* __restrict__ out, int n8) {
  int i = blockIdx.x * 256 + threadIdx.x;
  if (i >= n8) return;
  f32x4 a = *(const f32x4*)(in + (size_t)i * 8);
  f32x4 b = *(const f32x4*)(in + (size_t)i * 8 + 4);
  bf16x8 o;
  o[0]=f2bf(a[0]); o[1]=f2bf(a[1]); o[2]=f2bf(a[2]); o[3]=f2bf(a[3]);
  o[4]=f2bf(b[0]); o[5]=f2bf(b[1]); o[6]=f2bf(b[2]); o[7]=f2bf(b[3]);
  *(bf16x8*)(out + (size_t)i * 8) = o;
}

// ---------------- NT GEMM: C[M,N] = A[M,K](bf16) @ W[N,K](bf16)^T + bias ----------------
// 128x128 tile, BK=64, 256 threads (4 waves, 2x2), each wave 64x64 out.
// LDS layout [row][64] bf16, XOR-swizzled: 16B-unit ^= (row&7); staging pre-swizzles global src.
template<int RELU, int RES, int OUTF, int OUTB>
__global__ __launch_bounds__(256) void gemm_nt(
    const short* __restrict__ A, const short* __restrict__ W,
    const float* __restrict__ bias, const float* __restrict__ res,
    float* __restrict__ outF, short* __restrict__ outB,
    int M, int N, int K)
{
  __shared__ short As[128 * 64];
  __shared__ short Bs[128 * 64];
  const int tid = threadIdx.x, lane = tid & 63, wid = tid >> 6;
  const int wm = wid >> 1, wn = wid & 1;
  const int lrow = lane & 15, lk = lane >> 4;
  const int row0 = blockIdx.y * 128;
  const int col0 = blockIdx.x * 128;

  const f32x4 z4 = {0.f, 0.f, 0.f, 0.f};
  f32x4 acc[4][4];
#pragma unroll
  for (int i = 0; i < 4; ++i)
#pragma unroll
    for (int j = 0; j < 4; ++j) acc[i][j] = z4;

  // staging: thread -> (row = i*32 + tid/8, unit = tid%8), source unit pre-swizzled
  const int srow = tid >> 3;
  const int su = (tid & 7) ^ (srow & 7);
  const short* Abase = A + (size_t)(row0 + srow) * K + su * 8;
  const short* Wbase = W + (size_t)(col0 + srow) * K + su * 8;

  for (int kt = 0; kt < K; kt += 64) {
#pragma unroll
    for (int i = 0; i < 4; ++i) {
      gload_lds16(Abase + (size_t)i * 32 * K + kt, As + (i * 256 + wid * 64) * 8);
      gload_lds16(Wbase + (size_t)i * 32 * K + kt, Bs + (i * 256 + wid * 64) * 8);
    }
    __syncthreads();
#pragma unroll
    for (int kk = 0; kk < 2; ++kk) {
      bf16x8 af[4], bfr[4];
#pragma unroll
      for (int mi = 0; mi < 4; ++mi) {
        int row = wm * 64 + mi * 16 + lrow;
        af[mi] = *(const bf16x8*)(As + row * 64 + (((kk * 4 + lk) ^ (row & 7)) * 8));
      }
#pragma unroll
      for (int ni = 0; ni < 4; ++ni) {
        int row = wn * 64 + ni * 16 + lrow;
        bfr[ni] = *(const bf16x8*)(Bs + row * 64 + (((kk * 4 + lk) ^ (row & 7)) * 8));
      }
#pragma unroll
      for (int mi = 0; mi < 4; ++mi)
#pragma unroll
        for (int ni = 0; ni < 4; ++ni)
          acc[mi][ni] = __builtin_amdgcn_mfma_f32_16x16x32_bf16(af[mi], bfr[ni], acc[mi][ni], 0, 0, 0);
    }
    __syncthreads();
  }

#pragma unroll
  for (int mi = 0; mi < 4; ++mi) {
#pragma unroll
    for (int ni = 0; ni < 4; ++ni) {
      int col = col0 + wn * 64 + ni * 16 + lrow;
      float bv = bias[col];
#pragma unroll
      for (int r = 0; r < 4; ++r) {
        int row = row0 + wm * 64 + mi * 16 + lk * 4 + r;
        float v = acc[mi][ni][r] + bv;
        if (RELU) v = fmaxf(v, 0.f);
        size_t idx = (size_t)row * N + col;
        if (RES)  v += res[idx];
        if (OUTF) outF[idx] = v;
        if (OUTB) outB[idx] = f2bf(v);
      }
    }
  }
}

// ---------------- flash attention ----------------
// grid: (S/64, B*H). 4 waves x 16 q-rows. K,V tiles of 64 keys staged in LDS.
__global__ __launch_bounds__(256) void attn_flash(
    const short* __restrict__ Qm, const short* __restrict__ Km,
    const short* __restrict__ Vm, const int* __restrict__ mask,
    short* __restrict__ Om)
{
  __shared__ short Ks[64 * 64];        // [key][dk], swizzled
  __shared__ short Vt[64 * 64];        // [dk][key], swizzled
  __shared__ short Ps[4 * 16 * 64];    // per-wave P tile [q16][key64], swizzled

  const int tid = threadIdx.x, lane = tid & 63, wid = tid >> 6;
  const int lrow = lane & 15, lk = lane >> 4;
  const int bh = blockIdx.y, b = bh >> 4, h = bh & 15;
  const int q0 = blockIdx.x * 64 + wid * 16;

  const f32x4 z4 = {0.f, 0.f, 0.f, 0.f};
  bf16x8 qf[2];
#pragma unroll
  for (int kk = 0; kk < 2; ++kk)
    qf[kk] = *(const bf16x8*)(Qm + ((size_t)(b * SS + q0 + lrow)) * DD + h * 64 + kk * 32 + lk * 8);

  f32x4 acc[4];
#pragma unroll
  for (int nf = 0; nf < 4; ++nf) acc[nf] = z4;
  float m_r[4] = {-1e30f, -1e30f, -1e30f, -1e30f};
  float l_r[4] = {0.f, 0.f, 0.f, 0.f};

  const int srow = tid >> 3;
  const int su = (tid & 7) ^ (srow & 7);
  const short* Kbase = Km + ((size_t)(b * SS + srow)) * DD + h * 64 + su * 8;

  for (int kt = 0; kt < SS; kt += 64) {
    __syncthreads();   // previous tile fully consumed
    // stage K tile (async, swizzled source -> linear LDS)
#pragma unroll
    for (int i = 0; i < 2; ++i)
      gload_lds16(Kbase + ((size_t)(kt + i * 32)) * DD, Ks + (i * 256 + wid * 64) * 8);
    // stage V transposed: Vt[dk][key], unit ^= dk&7
#pragma unroll
    for (int i = 0; i < 2; ++i) {
      int idx = i * 256 + tid;
      int krow = idx >> 3, unit = idx & 7;
      bf16x8 v8 = *(const bf16x8*)(Vm + ((size_t)(b * SS + kt + krow)) * DD + h * 64 + unit * 8);
#pragma unroll
      for (int j = 0; j < 8; ++j) {
        int dk = unit * 8 + j;
        Vt[dk * 64 + ((((krow >> 3) ^ (dk & 7)) << 3) | (krow & 7))] = ((short*)&v8)[j];
      }
    }
    __syncthreads();

    // S = Q K^T
    f32x4 sf[4];
#pragma unroll
    for (int nf = 0; nf < 4; ++nf) sf[nf] = z4;
#pragma unroll
    for (int kk = 0; kk < 2; ++kk) {
#pragma unroll
      for (int nf = 0; nf < 4; ++nf) {
        int key = nf * 16 + lrow;
        bf16x8 kf = *(const bf16x8*)(Ks + key * 64 + (((kk * 4 + lk) ^ (key & 7)) * 8));
        sf[nf] = __builtin_amdgcn_mfma_f32_16x16x32_bf16(qf[kk], kf, sf[nf], 0, 0, 0);
      }
    }

    // scale + mask + online softmax (rows = lk*4+r, reduce across 16 lanes)
    float p[4][4];
    const int* mrow = mask + b * SS + kt;
#pragma unroll
    for (int nf = 0; nf < 4; ++nf) {
      int mv = mrow[nf * 16 + lrow];
#pragma unroll
      for (int r = 0; r < 4; ++r)
        p[nf][r] = (mv == 0) ? -1e9f : sf[nf][r] * 0.125f;
    }
#pragma unroll
    for (int r = 0; r < 4; ++r) {
      float mx = fmaxf(fmaxf(p[0][r], p[1][r]), fmaxf(p[2][r], p[3][r]));
#pragma unroll
      for (int o = 1; o < 16; o <<= 1) mx = fmaxf(mx, __shfl_xor(mx, o, 64));
      float mn = fmaxf(m_r[r], mx);
      float sc = expf(m_r[r] - mn);
      float rs = 0.f;
#pragma unroll
      for (int nf = 0; nf < 4; ++nf) { float e = expf(p[nf][r] - mn); p[nf][r] = e; rs += e; }
#pragma unroll
      for (int o = 1; o < 16; o <<= 1) rs += __shfl_xor(rs, o, 64);
      m_r[r] = mn;
      l_r[r] = l_r[r] * sc + rs;
#pragma unroll
      for (int nf = 0; nf < 4; ++nf) acc[nf][r] *= sc;
    }

    // P -> LDS (per-wave region, swizzled), then PV
    short* Pw = Ps + wid * 1024;
#pragma unroll
    for (int nf = 0; nf < 4; ++nf) {
      int col = nf * 16 + lrow;
#pragma unroll
      for (int r = 0; r < 4; ++r) {
        int rr = lk * 4 + r;
        Pw[rr * 64 + ((((col >> 3) ^ (rr & 7)) << 3) | (col & 7))] = f2bf(p[nf][r]);
      }
    }
    asm volatile("s_waitcnt lgkmcnt(0)" ::: "memory");
#pragma unroll
    for (int kk2 = 0; kk2 < 2; ++kk2) {
      bf16x8 pa = *(const bf16x8*)(Pw + lrow * 64 + (((kk2 * 4 + lk) ^ (lrow & 7)) * 8));
#pragma unroll
      for (int nf = 0; nf < 4; ++nf) {
        int dkc = nf * 16 + lrow;
        bf16x8 vf = *(const bf16x8*)(Vt + dkc * 64 + (((kk2 * 4 + lk) ^ (dkc & 7)) * 8));
        acc[nf] = __builtin_amdgcn_mfma_f32_16x16x32_bf16(pa, vf, acc[nf], 0, 0, 0);
      }
    }
  }

#pragma unroll
  for (int nf = 0; nf < 4; ++nf) {
    int dk = nf * 16 + lrow;
#pragma unroll
    for (int r = 0; r < 4; ++r) {
      int q = q0 + lk * 4 + r;
      Om[((size_t)(b * SS + q)) * DD + h * 64 + dk] = f2bf(acc[nf][r] / l_r[r]);
    }
  }
}

// ---------------- LayerNorm (ddof=1, eps added to sigma), in-place fp32 + optional bf16 ----------------
template<int WRITE_BF16>
__global__ __launch_bounds__(256) void layernorm_k(
    float* __restrict__ x, short* __restrict__ xb,
    const float* __restrict__ g, const float* __restrict__ be)
{
  const int row = blockIdx.x, tid = threadIdx.x;
  float* xr = x + (size_t)row * DD;
  f32x4 a = *(const f32x4*)(xr + tid * 4);
  float s  = a[0] + a[1] + a[2] + a[3];
  float ss = a[0]*a[0] + a[1]*a[1] + a[2]*a[2] + a[3]*a[3];
#pragma unroll
  for (int o = 1; o < 64; o <<= 1) { s += __shfl_xor(s, o, 64); ss += __shfl_xor(ss, o, 64); }
  __shared__ float red[8];
  const int wid = tid >> 6, lane = tid & 63;
  if (lane == 0) { red[wid] = s; red[4 + wid] = ss; }
  __syncthreads();
  s  = red[0] + red[1] + red[2] + red[3];
  ss = red[4] + red[5] + red[6] + red[7];
  float mu  = s * (1.f / DD);
  float var = fmaxf((ss - (float)DD * mu * mu) * (1.f / (DD - 1)), 0.f);
  float inv = g[0] / (1e-6f + sqrtf(var));
  float bb  = be[0];
#pragma unroll
  for (int j = 0; j < 4; ++j) a[j] = (a[j] - mu) * inv + bb;
  *(f32x4*)(xr + tid * 4) = a;
  if (WRITE_BF16) {
    s16x4 o;
#pragma unroll
    for (int j = 0; j < 4; ++j) o[j] = f2bf(a[j]);
    *(s16x4*)(xb + (size_t)row * DD + tid * 4) = o;
  }
}

// ---------------- launcher ----------------
extern "C" void kernel_launch(void* const* d_in, const int* in_sizes, int n_in,
                              void* d_out, int out_size, void* d_ws, size_t ws_size,
                              hipStream_t stream) {
  const float* x    = (const float*)d_in[0];
  const int*   mask = (const int*)d_in[1];
  const float* Wq = (const float*)d_in[2];  const float* bq = (const float*)d_in[3];
  const float* Wk = (const float*)d_in[4];  const float* bk = (const float*)d_in[5];
  const float* Wv = (const float*)d_in[6];  const float* bv = (const float*)d_in[7];
  const float* Wo = (const float*)d_in[8];  const float* bo = (const float*)d_in[9];
  const float* W1 = (const float*)d_in[10]; const float* b1 = (const float*)d_in[11];
  const float* W2 = (const float*)d_in[12]; const float* b2 = (const float*)d_in[13];
  const float* g1 = (const float*)d_in[14]; const float* be1 = (const float*)d_in[15];
  const float* g2 = (const float*)d_in[16]; const float* be2 = (const float*)d_in[17];
  float* out = (float*)d_out;

  char* ws = (char*)d_ws;
  size_t off = 0;
  auto alloc = [&](size_t bytes) -> char* {
    char* p = ws + off; off += (bytes + 255) & ~(size_t)255; return p;
  };
  short* xb  = (short*)alloc((size_t)MT * DD * 2);     // 16 MB, reused as x1b later
  short* wqb = (short*)alloc((size_t)DD * DD * 2);
  short* wkb = (short*)alloc((size_t)DD * DD * 2);
  short* wvb = (short*)alloc((size_t)DD * DD * 2);
  short* wob = (short*)alloc((size_t)DD * DD * 2);
  short* w1b = (short*)alloc((size_t)DFF * DD * 2);
  short* w2b = (short*)alloc((size_t)DD * DFF * 2);
  short* Qb  = (short*)alloc((size_t)MT * DD * 2);     // Qb/Kb/Vb/Ab contiguous: reused as F1
  short* Kb  = (short*)alloc((size_t)MT * DD * 2);
  short* Vb  = (short*)alloc((size_t)MT * DD * 2);
  short* Ab  = (short*)alloc((size_t)MT * DD * 2);
  float* x1  = (float*)alloc((size_t)MT * DD * 4);     // 32 MB
  short* F1  = Qb;                                     // [8192][4096] bf16 = 64 MB over Q/K/V/A block
  short* x1b = xb;

  // converts
  cvt_bf16<<<(MT * DD / 8 + 255) / 256, 256, 0, stream>>>(x, xb, MT * DD / 8);
  cvt_bf16<<<(DD * DD / 8 + 255) / 256, 256, 0, stream>>>(Wq, wqb, DD * DD / 8);
  cvt_bf16<<<(DD * DD / 8 + 255) / 256, 256, 0, stream>>>(Wk, wkb, DD * DD / 8);
  cvt_bf16<<<(DD * DD / 8 + 255) / 256, 256, 0, stream>>>(Wv, wvb, DD * DD / 8);
  cvt_bf16<<<(DD * DD / 8 + 255) / 256, 256, 0, stream>>>(Wo, wob, DD * DD / 8);
  cvt_bf16<<<(DFF * DD / 8 + 255) / 256, 256, 0, stream>>>(W1, w1b, DFF * DD / 8);
  cvt_bf16<<<(DD * DFF / 8 + 255) / 256, 256, 0, stream>>>(W2, w2b, DD * DFF / 8);

  // QKV projections (bf16 out)
  gemm_nt<0,0,0,1><<<dim3(DD/128, MT/128), 256, 0, stream>>>(xb, wqb, bq, nullptr, nullptr, Qb, MT, DD, DD);
  gemm_nt<0,0,0,1><<<dim3(DD/128, MT/128), 256, 0, stream>>>(xb, wkb, bk, nullptr, nullptr, Kb, MT, DD, DD);
  gemm_nt<0,0,0,1><<<dim3(DD/128, MT/128), 256, 0, stream>>>(xb, wvb, bv, nullptr, nullptr, Vb, MT, DD, DD);

  // attention
  attn_flash<<<dim3(SS/64, BB*HH), 256, 0, stream>>>(Qb, Kb, Vb, mask, Ab);

  // out proj + residual(x) -> x1 (fp32), then LN1 in-place (+bf16 copy)
  gemm_nt<0,1,1,0><<<dim3(DD/128, MT/128), 256, 0, stream>>>(Ab, wob, bo, x, x1, nullptr, MT, DD, DD);
  layernorm_k<1><<<MT, 256, 0, stream>>>(x1, x1b, g1, be1);

  // FF1 (ReLU, bf16 out), FF2 (+residual x1 -> d_out fp32), LN2 in-place on d_out
  gemm_nt<1,0,0,1><<<dim3(DFF/128, MT/128), 256, 0, stream>>>(x1b, w1b, b1, nullptr, nullptr, F1, MT, DFF, DD);
  gemm_nt<0,1,1,0><<<dim3(DD/128, MT/128), 256, 0, stream>>>(F1, w2b, b2, x1, out, nullptr, MT, DD, DFF);
  layernorm_k<0><<<MT, 256, 0, stream>>>(out, nullptr, g2, be2);
}

// Round 2
// 435.984 us; speedup vs baseline: 1.1968x; 1.1968x over previous
//
#include <hip/hip_runtime.h>
#include <stdint.h>

// Problem dims
#define BB 8
#define SS 1024
#define DD 1024
#define HH 16
#define DFF 4096
#define MT (BB*SS)   // 8192 tokens

typedef __attribute__((ext_vector_type(8))) short bf16x8;  // 8 bf16 in 4 VGPRs
typedef __attribute__((ext_vector_type(4))) short s16x4;
typedef __attribute__((ext_vector_type(4))) float f32x4;
typedef __attribute__((ext_vector_type(16))) float f32x16;
typedef unsigned int u32x2 __attribute__((ext_vector_type(2)));

#define LOG2E 1.44269504088896340736f

__device__ __forceinline__ short f2bf(float f) {
  union { float f; uint32_t u; } v; v.f = f;
  uint32_t r = v.u + 0x7FFFu + ((v.u >> 16) & 1u);   // RNE
  return (short)(r >> 16);
}

// async global->LDS, 16B per lane. LDS dest must be wave-uniform base (+lane*16 implicit).
__device__ __forceinline__ void gload_lds16(const void* g, void* l) {
  __builtin_amdgcn_global_load_lds(
      (__attribute__((address_space(1))) uint32_t*)(uintptr_t)g,
      (__attribute__((address_space(3))) uint32_t*)(uint32_t)(uintptr_t)l,
      16, 0, 0);
}

__device__ __forceinline__ uint32_t cvtpk(float lo, float hi) {
  uint32_t r;
  asm("v_cvt_pk_bf16_f32 %0, %1, %2" : "=v"(r) : "v"(lo), "v"(hi));
  return r;
}

// exchange: x = {a.lo32lanes, b.lo32lanes(from partner)}, y = {a.hi32lanes(from partner), b.hi32lanes}
__device__ __forceinline__ void swap2(uint32_t a, uint32_t b, uint32_t& x, uint32_t& y) {
#if __has_builtin(__builtin_amdgcn_permlane32_swap)
  u32x2 r = __builtin_amdgcn_permlane32_swap(a, b, false, false);
  x = r.x; y = r.y;
#else
  uint32_t asw = (uint32_t)__shfl_xor((int)a, 32, 64);
  uint32_t bsw = (uint32_t)__shfl_xor((int)b, 32, 64);
  bool h = (threadIdx.x & 32) != 0;
  x = h ? bsw : a;
  y = h ? b : asw;
#endif
}

// ---------------- fp32 -> bf16 convert ----------------
__global__ __launch_bounds__(256) void cvt_bf16(const float* __restrict__ in,
                                                short* __restrict__ out, int n8) {
  int i = blockIdx.x * 256 + threadIdx.x;
  if (i >= n8) return;
  f32x4 a = *(const f32x4*)(in + (size_t)i * 8);
  f32x4 b = *(const f32x4*)(in + (size_t)i * 8 + 4);
  bf16x8 o;
  o[0]=f2bf(a[0]); o[1]=f2bf(a[1]); o[2]=f2bf(a[2]); o[3]=f2bf(a[3]);
  o[4]=f2bf(b[0]); o[5]=f2bf(b[1]); o[6]=f2bf(b[2]); o[7]=f2bf(b[3]);
  *(bf16x8*)(out + (size_t)i * 8) = o;
}

// ---------------- NT GEMM: C[M,N] = A[M,K](bf16) @ W[N,K](bf16)^T + bias ----------------
template<int RELU, int RES, int OUTF, int OUTB>
__global__ __launch_bounds__(256) void gemm_nt(
    const short* __restrict__ A, const short* __restrict__ W,
    const float* __restrict__ bias, const float* __restrict__ res,
    float* __restrict__ outF, short* __restrict__ outB,
    int M, int N, int K)
{
  __shared__ short As[128 * 64];
  __shared__ short Bs[128 * 64];
  const int tid = threadIdx.x, lane = tid & 63, wid = tid >> 6;
  const int wm = wid >> 1, wn = wid & 1;
  const int lrow = lane & 15, lk = lane >> 4;
  const int row0 = blockIdx.y * 128;
  const int col0 = blockIdx.x * 128;

  const f32x4 z4 = {0.f, 0.f, 0.f, 0.f};
  f32x4 acc[4][4];
#pragma unroll
  for (int i = 0; i < 4; ++i)
#pragma unroll
    for (int j = 0; j < 4; ++j) acc[i][j] = z4;

  const int srow = tid >> 3;
  const int su = (tid & 7) ^ (srow & 7);
  const short* Abase = A + (size_t)(row0 + srow) * K + su * 8;
  const short* Wbase = W + (size_t)(col0 + srow) * K + su * 8;

  for (int kt = 0; kt < K; kt += 64) {
#pragma unroll
    for (int i = 0; i < 4; ++i) {
      gload_lds16(Abase + (size_t)i * 32 * K + kt, As + (i * 256 + wid * 64) * 8);
      gload_lds16(Wbase + (size_t)i * 32 * K + kt, Bs + (i * 256 + wid * 64) * 8);
    }
    __syncthreads();
#pragma unroll
    for (int kk = 0; kk < 2; ++kk) {
      bf16x8 af[4], bfr[4];
#pragma unroll
      for (int mi = 0; mi < 4; ++mi) {
        int row = wm * 64 + mi * 16 + lrow;
        af[mi] = *(const bf16x8*)(As + row * 64 + (((kk * 4 + lk) ^ (row & 7)) * 8));
      }
#pragma unroll
      for (int ni = 0; ni < 4; ++ni) {
        int row = wn * 64 + ni * 16 + lrow;
        bfr[ni] = *(const bf16x8*)(Bs + row * 64 + (((kk * 4 + lk) ^ (row & 7)) * 8));
      }
#pragma unroll
      for (int mi = 0; mi < 4; ++mi)
#pragma unroll
        for (int ni = 0; ni < 4; ++ni)
          acc[mi][ni] = __builtin_amdgcn_mfma_f32_16x16x32_bf16(af[mi], bfr[ni], acc[mi][ni], 0, 0, 0);
    }
    __syncthreads();
  }

#pragma unroll
  for (int mi = 0; mi < 4; ++mi) {
#pragma unroll
    for (int ni = 0; ni < 4; ++ni) {
      int col = col0 + wn * 64 + ni * 16 + lrow;
      float bv = bias[col];
#pragma unroll
      for (int r = 0; r < 4; ++r) {
        int row = row0 + wm * 64 + mi * 16 + lk * 4 + r;
        float v = acc[mi][ni][r] + bv;
        if (RELU) v = fmaxf(v, 0.f);
        size_t idx = (size_t)row * N + col;
        if (RES)  v += res[idx];
        if (OUTF) outF[idx] = v;
        if (OUTB) outB[idx] = f2bf(v);
      }
    }
  }
}

// ---------------- V transpose: Vb[b*SS+s][h*64+dk] -> Vt[(bh*64+dk)][s] ----------------
__global__ __launch_bounds__(256) void transpose_v(const short* __restrict__ Vb,
                                                   short* __restrict__ Vt) {
  const int s = blockIdx.x * 256 + threadIdx.x;
  const int u = blockIdx.y;                       // dk group of 8
  const int bh = blockIdx.z, b = bh >> 4, h = bh & 15;
  bf16x8 v = *(const bf16x8*)(Vb + ((size_t)(b * SS + s)) * DD + h * 64 + u * 8);
  size_t ob = ((size_t)bh * 64 + u * 8) * SS + s;
#pragma unroll
  for (int j = 0; j < 8; ++j) Vt[ob + (size_t)j * SS] = v[j];
}

// ---------------- flash attention, 32x32 swapped-QK^T structure ----------------
// grid: (SS/128, B*H). 4 waves x 32 q-rows. 64-key tiles; K and V^T staged via global_load_lds.
__global__ __launch_bounds__(256) void attn_flash2(
    const short* __restrict__ Qm, const short* __restrict__ Km,
    const short* __restrict__ Vtg, const int* __restrict__ mask,
    short* __restrict__ Om)
{
  __shared__ short Ks[64 * 64];   // [key][dk], 16B-unit XOR-swizzled by (key&7)
  __shared__ short Vs[64 * 64];   // [dk][key], 16B-unit XOR-swizzled by (dk&7)
  __shared__ float ma[64];        // additive mask for current key tile
  __shared__ float fb[4 * 32];    // per-wave per-q broadcast slab

  const int tid = threadIdx.x, lane = tid & 63, wid = tid >> 6;
  const int l31 = lane & 31, hi = lane >> 5;
  const int bh = blockIdx.y, b = bh >> 4, h = bh & 15;
  const int q0 = blockIdx.x * 128 + wid * 32;

  // Q fragments (B-operand of swapped QK^T): qf[t][j] = Q[q=l31][dk=t*16+hi*8+j]
  bf16x8 qf[4];
  {
    const short* qrow = Qm + ((size_t)(b * SS + q0 + l31)) * DD + h * 64;
#pragma unroll
    for (int t = 0; t < 4; ++t) qf[t] = *(const bf16x8*)(qrow + t * 16 + hi * 8);
  }

  f32x16 acc0, acc1;              // O tiles: rows q(reg,hi), cols dk = n*32 + l31
#pragma unroll
  for (int i = 0; i < 16; ++i) { acc0[i] = 0.f; acc1[i] = 0.f; }
  float m_r = -3e38f, l_r = 0.f;

  const int srow = tid >> 3;
  const int su = tid & 7;

  for (int kt = 0; kt < SS; kt += 64) {
    __syncthreads();              // previous tile fully consumed
#pragma unroll
    for (int i = 0; i < 2; ++i) {
      int r = i * 32 + srow;
      int uu = su ^ (r & 7);
      gload_lds16(Km + ((size_t)(b * SS + kt + r)) * DD + h * 64 + uu * 8,
                  Ks + i * 2048 + wid * 512);
      gload_lds16(Vtg + ((size_t)(bh * 64 + r)) * SS + kt + uu * 8,
                  Vs + i * 2048 + wid * 512);
    }
    if (tid < 64) ma[tid] = (mask[b * SS + kt + tid] == 0) ? -1e9f : 0.f;
    __syncthreads();              // implies vmcnt(0)+lgkmcnt(0) drain

    // S^T[key][q] = K·Q^T : two 32-key tiles
    f32x16 s0, s1;
#pragma unroll
    for (int i = 0; i < 16; ++i) { s0[i] = 0.f; s1[i] = 0.f; }
#pragma unroll
    for (int t = 0; t < 4; ++t) {
      int u = (t * 2 + hi) ^ (l31 & 7);
      bf16x8 k0 = *(const bf16x8*)(Ks + l31 * 64 + u * 8);
      bf16x8 k1 = *(const bf16x8*)(Ks + (32 + l31) * 64 + u * 8);
      s0 = __builtin_amdgcn_mfma_f32_32x32x16_bf16(k0, qf[t], s0, 0, 0, 0);
      s1 = __builtin_amdgcn_mfma_f32_32x32x16_bf16(k1, qf[t], s1, 0, 0, 0);
    }

    // scale + mask + online softmax. lane owns q = l31 (replicated across hi halves);
    // reg -> key(reg,hi) = (reg&3) + 8*(reg>>2) + 4*hi
    float p0[16], p1[16];
    float mx = -3e38f;
#pragma unroll
    for (int g = 0; g < 4; ++g) {
      f32x4 a0 = *(const f32x4*)(ma + g * 8 + hi * 4);
      f32x4 a1 = *(const f32x4*)(ma + 32 + g * 8 + hi * 4);
#pragma unroll
      for (int j = 0; j < 4; ++j) {
        float v0 = s0[g * 4 + j] * 0.125f + a0[j];
        float v1 = s1[g * 4 + j] * 0.125f + a1[j];
        p0[g * 4 + j] = v0; p1[g * 4 + j] = v1;
        mx = fmaxf(mx, fmaxf(v0, v1));
      }
    }
    mx = fmaxf(mx, __shfl_xor(mx, 32, 64));
    float mn  = fmaxf(m_r, mx);
    float fac = exp2f((m_r - mn) * LOG2E);
    m_r = mn;
    float mnl = mn * LOG2E;
    float rs = 0.f;
#pragma unroll
    for (int r = 0; r < 16; ++r) {
      p0[r] = exp2f(p0[r] * LOG2E - mnl);
      p1[r] = exp2f(p1[r] * LOG2E - mnl);
      rs += p0[r] + p1[r];
    }
    rs += __shfl_xor(rs, 32, 64);
    l_r = l_r * fac + rs;

    // rescale acc: factor per q(reg,hi) via per-wave LDS broadcast
    fb[wid * 32 + l31] = fac;
#pragma unroll
    for (int g = 0; g < 4; ++g) {
      f32x4 fv = *(const f32x4*)(fb + wid * 32 + g * 8 + hi * 4);
#pragma unroll
      for (int j = 0; j < 4; ++j) { acc0[g * 4 + j] *= fv[j]; acc1[g * 4 + j] *= fv[j]; }
    }

    // P -> bf16 A-fragments fully in-register: 16 cvt_pk + 8 permlane32_swap
    uint32_t w0[8], w1[8];
#pragma unroll
    for (int m = 0; m < 8; ++m) {
      w0[m] = cvtpk(p0[2 * m], p0[2 * m + 1]);
      w1[m] = cvtpk(p1[2 * m], p1[2 * m + 1]);
    }
    uint32_t pa[4][4];
    swap2(w0[0], w0[2], pa[0][0], pa[0][2]);
    swap2(w0[1], w0[3], pa[0][1], pa[0][3]);
    swap2(w0[4], w0[6], pa[1][0], pa[1][2]);
    swap2(w0[5], w0[7], pa[1][1], pa[1][3]);
    swap2(w1[0], w1[2], pa[2][0], pa[2][2]);
    swap2(w1[1], w1[3], pa[2][1], pa[2][3]);
    swap2(w1[4], w1[6], pa[3][0], pa[3][2]);
    swap2(w1[5], w1[7], pa[3][1], pa[3][3]);

    // PV: acc[q][dk] += P[q][key] * V[key][dk]; V fragment read from Vt rows
#pragma unroll
    for (int kc = 0; kc < 4; ++kc) {
      union { uint32_t w[4]; bf16x8 v; } pu;
      pu.w[0] = pa[kc][0]; pu.w[1] = pa[kc][1]; pu.w[2] = pa[kc][2]; pu.w[3] = pa[kc][3];
      int u = (kc * 2 + hi) ^ (l31 & 7);
      bf16x8 v0 = *(const bf16x8*)(Vs + l31 * 64 + u * 8);
      bf16x8 v1 = *(const bf16x8*)(Vs + (32 + l31) * 64 + u * 8);
      acc0 = __builtin_amdgcn_mfma_f32_32x32x16_bf16(pu.v, v0, acc0, 0, 0, 0);
      acc1 = __builtin_amdgcn_mfma_f32_32x32x16_bf16(pu.v, v1, acc1, 0, 0, 0);
    }
  }

  // epilogue: divide by l (per-q broadcast) and store
  fb[wid * 32 + l31] = 1.f / l_r;
#pragma unroll
  for (int g = 0; g < 4; ++g) {
    f32x4 rv = *(const f32x4*)(fb + wid * 32 + g * 8 + hi * 4);
#pragma unroll
    for (int j = 0; j < 4; ++j) {
      int q = q0 + g * 8 + hi * 4 + j;
      size_t base = ((size_t)(b * SS + q)) * DD + h * 64 + l31;
      Om[base]      = f2bf(acc0[g * 4 + j] * rv[j]);
      Om[base + 32] = f2bf(acc1[g * 4 + j] * rv[j]);
    }
  }
}

// ---------------- LayerNorm (ddof=1, eps added to sigma) ----------------
template<int WRITE_BF16>
__global__ __launch_bounds__(256) void layernorm_k(
    float* __restrict__ x, short* __restrict__ xb,
    const float* __restrict__ g, const float* __restrict__ be)
{
  const int row = blockIdx.x, tid = threadIdx.x;
  float* xr = x + (size_t)row * DD;
  f32x4 a = *(const f32x4*)(xr + tid * 4);
  float s  = a[0] + a[1] + a[2] + a[3];
  float ss = a[0]*a[0] + a[1]*a[1] + a[2]*a[2] + a[3]*a[3];
#pragma unroll
  for (int o = 1; o < 64; o <<= 1) { s += __shfl_xor(s, o, 64); ss += __shfl_xor(ss, o, 64); }
  __shared__ float red[8];
  const int wid = tid >> 6, lane = tid & 63;
  if (lane == 0) { red[wid] = s; red[4 + wid] = ss; }
  __syncthreads();
  s  = red[0] + red[1] + red[2] + red[3];
  ss = red[4] + red[5] + red[6] + red[7];
  float mu  = s * (1.f / DD);
  float var = fmaxf((ss - (float)DD * mu * mu) * (1.f / (DD - 1)), 0.f);
  float inv = g[0] / (1e-6f + sqrtf(var));
  float bb  = be[0];
#pragma unroll
  for (int j = 0; j < 4; ++j) a[j] = (a[j] - mu) * inv + bb;
  *(f32x4*)(xr + tid * 4) = a;
  if (WRITE_BF16) {
    s16x4 o;
#pragma unroll
    for (int j = 0; j < 4; ++j) o[j] = f2bf(a[j]);
    *(s16x4*)(xb + (size_t)row * DD + tid * 4) = o;
  }
}

// ---------------- launcher ----------------
extern "C" void kernel_launch(void* const* d_in, const int* in_sizes, int n_in,
                              void* d_out, int out_size, void* d_ws, size_t ws_size,
                              hipStream_t stream) {
  const float* x    = (const float*)d_in[0];
  const int*   mask = (const int*)d_in[1];
  const float* Wq = (const float*)d_in[2];  const float* bq = (const float*)d_in[3];
  const float* Wk = (const float*)d_in[4];  const float* bk = (const float*)d_in[5];
  const float* Wv = (const float*)d_in[6];  const float* bv = (const float*)d_in[7];
  const float* Wo = (const float*)d_in[8];  const float* bo = (const float*)d_in[9];
  const float* W1 = (const float*)d_in[10]; const float* b1 = (const float*)d_in[11];
  const float* W2 = (const float*)d_in[12]; const float* b2 = (const float*)d_in[13];
  const float* g1 = (const float*)d_in[14]; const float* be1 = (const float*)d_in[15];
  const float* g2 = (const float*)d_in[16]; const float* be2 = (const float*)d_in[17];
  float* out = (float*)d_out;

  char* ws = (char*)d_ws;
  size_t off = 0;
  auto alloc = [&](size_t bytes) -> char* {
    char* p = ws + off; off += (bytes + 255) & ~(size_t)255; return p;
  };
  short* xb  = (short*)alloc((size_t)MT * DD * 2);
  short* wqb = (short*)alloc((size_t)DD * DD * 2);
  short* wkb = (short*)alloc((size_t)DD * DD * 2);
  short* wvb = (short*)alloc((size_t)DD * DD * 2);
  short* wob = (short*)alloc((size_t)DD * DD * 2);
  short* w1b = (short*)alloc((size_t)DFF * DD * 2);
  short* w2b = (short*)alloc((size_t)DD * DFF * 2);
  short* Qb  = (short*)alloc((size_t)MT * DD * 2);   // Q/K/V/A block reused as F1
  short* Kb  = (short*)alloc((size_t)MT * DD * 2);
  short* Vb  = (short*)alloc((size_t)MT * DD * 2);
  short* Ab  = (short*)alloc((size_t)MT * DD * 2);
  float* x1  = (float*)alloc((size_t)MT * DD * 4);   // 32 MB; first 16 MB doubles as Vt
  short* F1  = Qb;
  short* x1b = xb;
  short* Vt  = (short*)x1;   // Vt live only until attention completes; x1 written after

  cvt_bf16<<<(MT * DD / 8 + 255) / 256, 256, 0, stream>>>(x, xb, MT * DD / 8);
  cvt_bf16<<<(DD * DD / 8 + 255) / 256, 256, 0, stream>>>(Wq, wqb, DD * DD / 8);
  cvt_bf16<<<(DD * DD / 8 + 255) / 256, 256, 0, stream>>>(Wk, wkb, DD * DD / 8);
  cvt_bf16<<<(DD * DD / 8 + 255) / 256, 256, 0, stream>>>(Wv, wvb, DD * DD / 8);
  cvt_bf16<<<(DD * DD / 8 + 255) / 256, 256, 0, stream>>>(Wo, wob, DD * DD / 8);
  cvt_bf16<<<(DFF * DD / 8 + 255) / 256, 256, 0, stream>>>(W1, w1b, DFF * DD / 8);
  cvt_bf16<<<(DD * DFF / 8 + 255) / 256, 256, 0, stream>>>(W2, w2b, DD * DFF / 8);

  gemm_nt<0,0,0,1><<<dim3(DD/128, MT/128), 256, 0, stream>>>(xb, wqb, bq, nullptr, nullptr, Qb, MT, DD, DD);
  gemm_nt<0,0,0,1><<<dim3(DD/128, MT/128), 256, 0, stream>>>(xb, wkb, bk, nullptr, nullptr, Kb, MT, DD, DD);
  gemm_nt<0,0,0,1><<<dim3(DD/128, MT/128), 256, 0, stream>>>(xb, wvb, bv, nullptr, nullptr, Vb, MT, DD, DD);

  transpose_v<<<dim3(SS/256, 8, BB*HH), 256, 0, stream>>>(Vb, Vt);
  attn_flash2<<<dim3(SS/128, BB*HH), 256, 0, stream>>>(Qb, Kb, Vt, mask, Ab);

  gemm_nt<0,1,1,0><<<dim3(DD/128, MT/128), 256, 0, stream>>>(Ab, wob, bo, x, x1, nullptr, MT, DD, DD);
  layernorm_k<1><<<MT, 256, 0, stream>>>(x1, x1b, g1, be1);

  gemm_nt<1,0,0,1><<<dim3(DFF/128, MT/128), 256, 0, stream>>>(x1b, w1b, b1, nullptr, nullptr, F1, MT, DFF, DD);
  gemm_nt<0,1,1,0><<<dim3(DD/128, MT/128), 256, 0, stream>>>(F1, w2b, b2, x1, out, nullptr, MT, DD, DFF);
  layernorm_k<0><<<MT, 256, 0, stream>>>(out, nullptr, g2, be2);
}

// Round 4
// 400.760 us; speedup vs baseline: 1.3020x; 1.0879x over previous
//
#include <hip/hip_runtime.h>
#include <stdint.h>

// Problem dims
#define BB 8
#define SS 1024
#define DD 1024
#define HH 16
#define DFF 4096
#define MT (BB*SS)   // 8192 tokens

typedef __attribute__((ext_vector_type(8))) short bf16x8;  // 8 bf16 in 4 VGPRs
typedef __attribute__((ext_vector_type(4))) short s16x4;
typedef __attribute__((ext_vector_type(4))) float f32x4;
typedef __attribute__((ext_vector_type(16))) float f32x16;
typedef unsigned int u32x2 __attribute__((ext_vector_type(2)));

#define LOG2E 1.44269504088896340736f

__device__ __forceinline__ short f2bf(float f) {
  union { float f; uint32_t u; } v; v.f = f;
  uint32_t r = v.u + 0x7FFFu + ((v.u >> 16) & 1u);   // RNE
  return (short)(r >> 16);
}

// async global->LDS, 16B per lane. LDS dest must be wave-uniform base (+lane*16 implicit).
__device__ __forceinline__ void gload_lds16(const void* g, void* l) {
  __builtin_amdgcn_global_load_lds(
      (__attribute__((address_space(1))) uint32_t*)(uintptr_t)g,
      (__attribute__((address_space(3))) uint32_t*)(uint32_t)(uintptr_t)l,
      16, 0, 0);
}

__device__ __forceinline__ uint32_t cvtpk(float lo, float hi) {
  uint32_t r;
  asm("v_cvt_pk_bf16_f32 %0, %1, %2" : "=v"(r) : "v"(lo), "v"(hi));
  return r;
}

__device__ __forceinline__ void swap2(uint32_t a, uint32_t b, uint32_t& x, uint32_t& y) {
#if __has_builtin(__builtin_amdgcn_permlane32_swap)
  u32x2 r = __builtin_amdgcn_permlane32_swap(a, b, false, false);
  x = r.x; y = r.y;
#else
  uint32_t asw = (uint32_t)__shfl_xor((int)a, 32, 64);
  uint32_t bsw = (uint32_t)__shfl_xor((int)b, 32, 64);
  bool h = (threadIdx.x & 32) != 0;
  x = h ? bsw : a;
  y = h ? b : asw;
#endif
}

// ---------------- fp32 -> bf16 convert ----------------
__global__ __launch_bounds__(256) void cvt_bf16(const float* __restrict__ in,
                                                short* __restrict__ out, int n8) {
  int i = blockIdx.x * 256 + threadIdx.x;
  if (i >= n8) return;
  f32x4 a = *(const f32x4*)(in + (size_t)i * 8);
  f32x4 b = *(const f32x4*)(in + (size_t)i * 8 + 4);
  bf16x8 o;
  o[0]=f2bf(a[0]); o[1]=f2bf(a[1]); o[2]=f2bf(a[2]); o[3]=f2bf(a[3]);
  o[4]=f2bf(b[0]); o[5]=f2bf(b[1]); o[6]=f2bf(b[2]); o[7]=f2bf(b[3]);
  *(bf16x8*)(out + (size_t)i * 8) = o;
}

// ---------------- ring-pipelined NT GEMM ----------------
// C[M,N] = A[M,K] @ W[N,K]^T + bias.  BM x 256 tile, BK=32, 512 threads (8 waves, 2Mx4N).
// 3-slot LDS ring, prefetch depth 2, counted vmcnt (never 0 in loop), raw s_barrier.
// LDS line layout: 2 matrix rows per 128B line, 16B-unit ^= (line&3)  -> 2-way bank access (free).
// addr(row, ku) = (row>>1)*128 + (row&1)*64 + ((ku ^ ((row>>1)&3))*16)
template<int BM, int RELU, int RES, int OUTF, int OUTB, int QKV>
__global__ __launch_bounds__(512, 2) void gemm_ring(
    const short* __restrict__ A, const short* __restrict__ W,
    const float* __restrict__ bq, const float* __restrict__ bk,
    const float* __restrict__ bv, const float* __restrict__ res,
    float* __restrict__ outF, short* __restrict__ outB,
    int M, int N, int K)
{
  constexpr int AISS   = BM / 128;             // A gload issues per wave per tile
  constexpr int SLOT_A = BM * 32 * 2;          // bytes
  constexpr int SLOT   = SLOT_A + 256 * 32 * 2;
  constexpr int MI     = BM / 32;
  __shared__ __align__(16) char lds[3 * SLOT];

  const int tid = threadIdx.x, lane = tid & 63, wid = tid >> 6;
  const int wm = wid >> 2, wn = wid & 3;
  const int lrow = lane & 15, lk = lane >> 4;

  // XCD-chunked block swizzle (grid % 8 == 0 for all our launches)
  const int nwg = gridDim.x;
  const int cpx = nwg >> 3;
  const int id  = blockIdx.x;
  const int wg  = (id & 7) * cpx + (id >> 3);
  const int gx  = N >> 8;
  const int bx  = wg % gx, by = wg / gx;
  const int row0 = by * BM, col0 = bx * 256;

  // ---- staging lane decomposition ----
  const int lineo = lane >> 3;
  const int rin   = lineo * 2 + ((lane >> 2) & 1);
  const int ksrc  = (lane & 3) ^ (lineo & 3);

  const short* Asrc[AISS];
#pragma unroll
  for (int j = 0; j < AISS; ++j)
    Asrc[j] = A + (size_t)(row0 + (wid * AISS + j) * 16 + rin) * K + ksrc * 8;
  const short* Bsrc[2];
#pragma unroll
  for (int j = 0; j < 2; ++j)
    Bsrc[j] = W + (size_t)(col0 + (wid * 2 + j) * 16 + rin) * K + ksrc * 8;

  const f32x4 z4 = {0.f, 0.f, 0.f, 0.f};
  f32x4 acc[MI][4];
#pragma unroll
  for (int i = 0; i < MI; ++i)
#pragma unroll
    for (int j = 0; j < 4; ++j) acc[i][j] = z4;

  const int NT = K >> 5;

  auto stage = [&](int ts, int s) {
    char* base = lds + s * SLOT;
    int ko = ts * 32;
#pragma unroll
    for (int j = 0; j < AISS; ++j)
      gload_lds16(Asrc[j] + ko, base + (wid * AISS + j) * 1024);
#pragma unroll
    for (int j = 0; j < 2; ++j)
      gload_lds16(Bsrc[j] + ko, base + SLOT_A + (wid * 2 + j) * 1024);
  };

  // prologue: tiles 0,1 -> slots 0,1
  stage(0, 0);
  stage(1, 1);

  const int laneterm = (lrow >> 1) * 128 + (lrow & 1) * 64 + ((lk ^ ((lrow >> 1) & 3)) * 16);

  int sr = 0;
  for (int t = 0; t < NT; ++t) {
    const int sw = (sr == 0) ? 2 : sr - 1;         // (t+2)%3
    const int ts = (t + 2 < NT) ? t + 2 : NT - 1;  // tail clamp (dup stage, harmless)
    stage(ts, sw);
    if (AISS == 2) asm volatile("s_waitcnt vmcnt(8)" ::: "memory");
    else           asm volatile("s_waitcnt vmcnt(6)" ::: "memory");
    __builtin_amdgcn_s_barrier();
    __builtin_amdgcn_sched_barrier(0);

    const char* As = lds + sr * SLOT;
    const char* Bs = As + SLOT_A;
    bf16x8 af[MI], bfr[4];
#pragma unroll
    for (int mi = 0; mi < MI; ++mi)
      af[mi] = *(const bf16x8*)(As + wm * (BM * 32) + mi * 1024 + laneterm);
#pragma unroll
    for (int ni = 0; ni < 4; ++ni)
      bfr[ni] = *(const bf16x8*)(Bs + wn * 4096 + ni * 1024 + laneterm);

    __builtin_amdgcn_s_setprio(1);
#pragma unroll
    for (int mi = 0; mi < MI; ++mi)
#pragma unroll
      for (int ni = 0; ni < 4; ++ni)
        acc[mi][ni] = __builtin_amdgcn_mfma_f32_16x16x32_bf16(af[mi], bfr[ni], acc[mi][ni], 0, 0, 0);
    __builtin_amdgcn_s_setprio(0);

    __builtin_amdgcn_s_barrier();
    sr = (sr == 2) ? 0 : sr + 1;
  }

  // ---- epilogue ----
  const int sel    = QKV ? (col0 >> 10) : 0;
  const float* bias = QKV ? (sel == 0 ? bq : (sel == 1 ? bk : bv)) : bq;
  const int strideN = QKV ? 1024 : N;
  short* outBp = OUTB ? (outB + (QKV ? (size_t)sel * MT * DD : 0)) : outB;

#pragma unroll
  for (int mi = 0; mi < MI; ++mi) {
#pragma unroll
    for (int ni = 0; ni < 4; ++ni) {
      int col  = col0 + wn * 64 + ni * 16 + lrow;
      int coll = QKV ? (col & 1023) : col;
      float bvv = bias[coll];
#pragma unroll
      for (int r = 0; r < 4; ++r) {
        int row = row0 + wm * (BM / 2) + mi * 16 + lk * 4 + r;
        float v = acc[mi][ni][r] + bvv;
        if (RELU) v = fmaxf(v, 0.f);
        size_t idx = (size_t)row * strideN + coll;
        if (RES)  v += res[idx];
        if (OUTF) outF[idx] = v;
        if (OUTB) outBp[idx] = f2bf(v);
      }
    }
  }
}

// ---------------- V transpose: Vb[b*SS+s][h*64+dk] -> Vt[(bh*64+dk)][s] ----------------
__global__ __launch_bounds__(256) void transpose_v(const short* __restrict__ Vb,
                                                   short* __restrict__ Vt) {
  const int s = blockIdx.x * 256 + threadIdx.x;
  const int u = blockIdx.y;                       // dk group of 8
  const int bh = blockIdx.z, b = bh >> 4, h = bh & 15;
  bf16x8 v = *(const bf16x8*)(Vb + ((size_t)(b * SS + s)) * DD + h * 64 + u * 8);
  size_t ob = ((size_t)bh * 64 + u * 8) * SS + s;
#pragma unroll
  for (int j = 0; j < 8; ++j) Vt[ob + (size_t)j * SS] = v[j];
}

// ---------------- flash attention, 32x32 swapped-QK^T structure ----------------
__global__ __launch_bounds__(256) void attn_flash2(
    const short* __restrict__ Qm, const short* __restrict__ Km,
    const short* __restrict__ Vtg, const int* __restrict__ mask,
    short* __restrict__ Om)
{
  __shared__ short Ks[64 * 64];
  __shared__ short Vs[64 * 64];
  __shared__ float ma[64];
  __shared__ float fb[4 * 32];

  const int tid = threadIdx.x, lane = tid & 63, wid = tid >> 6;
  const int l31 = lane & 31, hi = lane >> 5;
  const int bh = blockIdx.y, b = bh >> 4, h = bh & 15;
  const int q0 = blockIdx.x * 128 + wid * 32;

  bf16x8 qf[4];
  {
    const short* qrow = Qm + ((size_t)(b * SS + q0 + l31)) * DD + h * 64;
#pragma unroll
    for (int t = 0; t < 4; ++t) qf[t] = *(const bf16x8*)(qrow + t * 16 + hi * 8);
  }

  f32x16 acc0, acc1;
#pragma unroll
  for (int i = 0; i < 16; ++i) { acc0[i] = 0.f; acc1[i] = 0.f; }
  float m_r = -3e38f, l_r = 0.f;

  const int srow = tid >> 3;
  const int su = tid & 7;

  for (int kt = 0; kt < SS; kt += 64) {
    __syncthreads();
#pragma unroll
    for (int i = 0; i < 2; ++i) {
      int r = i * 32 + srow;
      int uu = su ^ (r & 7);
      gload_lds16(Km + ((size_t)(b * SS + kt + r)) * DD + h * 64 + uu * 8,
                  Ks + i * 2048 + wid * 512);
      gload_lds16(Vtg + ((size_t)(bh * 64 + r)) * SS + kt + uu * 8,
                  Vs + i * 2048 + wid * 512);
    }
    if (tid < 64) ma[tid] = (mask[b * SS + kt + tid] == 0) ? -1e9f : 0.f;
    __syncthreads();

    f32x16 s0, s1;
#pragma unroll
    for (int i = 0; i < 16; ++i) { s0[i] = 0.f; s1[i] = 0.f; }
#pragma unroll
    for (int t = 0; t < 4; ++t) {
      int u = (t * 2 + hi) ^ (l31 & 7);
      bf16x8 k0 = *(const bf16x8*)(Ks + l31 * 64 + u * 8);
      bf16x8 k1 = *(const bf16x8*)(Ks + (32 + l31) * 64 + u * 8);
      s0 = __builtin_amdgcn_mfma_f32_32x32x16_bf16(k0, qf[t], s0, 0, 0, 0);
      s1 = __builtin_amdgcn_mfma_f32_32x32x16_bf16(k1, qf[t], s1, 0, 0, 0);
    }

    float p0[16], p1[16];
    float mx = -3e38f;
#pragma unroll
    for (int g = 0; g < 4; ++g) {
      f32x4 a0 = *(const f32x4*)(ma + g * 8 + hi * 4);
      f32x4 a1 = *(const f32x4*)(ma + 32 + g * 8 + hi * 4);
#pragma unroll
      for (int j = 0; j < 4; ++j) {
        float v0 = s0[g * 4 + j] * 0.125f + a0[j];
        float v1 = s1[g * 4 + j] * 0.125f + a1[j];
        p0[g * 4 + j] = v0; p1[g * 4 + j] = v1;
        mx = fmaxf(mx, fmaxf(v0, v1));
      }
    }
    mx = fmaxf(mx, __shfl_xor(mx, 32, 64));
    float mn  = fmaxf(m_r, mx);
    float fac = exp2f((m_r - mn) * LOG2E);
    m_r = mn;
    float mnl = mn * LOG2E;
    float rs = 0.f;
#pragma unroll
    for (int r = 0; r < 16; ++r) {
      p0[r] = exp2f(p0[r] * LOG2E - mnl);
      p1[r] = exp2f(p1[r] * LOG2E - mnl);
      rs += p0[r] + p1[r];
    }
    rs += __shfl_xor(rs, 32, 64);
    l_r = l_r * fac + rs;

    fb[wid * 32 + l31] = fac;
#pragma unroll
    for (int g = 0; g < 4; ++g) {
      f32x4 fv = *(const f32x4*)(fb + wid * 32 + g * 8 + hi * 4);
#pragma unroll
      for (int j = 0; j < 4; ++j) { acc0[g * 4 + j] *= fv[j]; acc1[g * 4 + j] *= fv[j]; }
    }

    uint32_t w0[8], w1[8];
#pragma unroll
    for (int m = 0; m < 8; ++m) {
      w0[m] = cvtpk(p0[2 * m], p0[2 * m + 1]);
      w1[m] = cvtpk(p1[2 * m], p1[2 * m + 1]);
    }
    uint32_t pa[4][4];
    swap2(w0[0], w0[2], pa[0][0], pa[0][2]);
    swap2(w0[1], w0[3], pa[0][1], pa[0][3]);
    swap2(w0[4], w0[6], pa[1][0], pa[1][2]);
    swap2(w0[5], w0[7], pa[1][1], pa[1][3]);
    swap2(w1[0], w1[2], pa[2][0], pa[2][2]);
    swap2(w1[1], w1[3], pa[2][1], pa[2][3]);
    swap2(w1[4], w1[6], pa[3][0], pa[3][2]);
    swap2(w1[5], w1[7], pa[3][1], pa[3][3]);

#pragma unroll
    for (int kc = 0; kc < 4; ++kc) {
      union { uint32_t w[4]; bf16x8 v; } pu;
      pu.w[0] = pa[kc][0]; pu.w[1] = pa[kc][1]; pu.w[2] = pa[kc][2]; pu.w[3] = pa[kc][3];
      int u = (kc * 2 + hi) ^ (l31 & 7);
      bf16x8 v0 = *(const bf16x8*)(Vs + l31 * 64 + u * 8);
      bf16x8 v1 = *(const bf16x8*)(Vs + (32 + l31) * 64 + u * 8);
      acc0 = __builtin_amdgcn_mfma_f32_32x32x16_bf16(pu.v, v0, acc0, 0, 0, 0);
      acc1 = __builtin_amdgcn_mfma_f32_32x32x16_bf16(pu.v, v1, acc1, 0, 0, 0);
    }
  }

  fb[wid * 32 + l31] = 1.f / l_r;
#pragma unroll
  for (int g = 0; g < 4; ++g) {
    f32x4 rv = *(const f32x4*)(fb + wid * 32 + g * 8 + hi * 4);
#pragma unroll
    for (int j = 0; j < 4; ++j) {
      int q = q0 + g * 8 + hi * 4 + j;
      size_t base = ((size_t)(b * SS + q)) * DD + h * 64 + l31;
      Om[base]      = f2bf(acc0[g * 4 + j] * rv[j]);
      Om[base + 32] = f2bf(acc1[g * 4 + j] * rv[j]);
    }
  }
}

// ---------------- LayerNorm (ddof=1, eps added to sigma) ----------------
template<int WRITE_BF16>
__global__ __launch_bounds__(256) void layernorm_k(
    float* __restrict__ x, short* __restrict__ xb,
    const float* __restrict__ g, const float* __restrict__ be)
{
  const int row = blockIdx.x, tid = threadIdx.x;
  float* xr = x + (size_t)row * DD;
  f32x4 a = *(const f32x4*)(xr + tid * 4);
  float s  = a[0] + a[1] + a[2] + a[3];
  float ss = a[0]*a[0] + a[1]*a[1] + a[2]*a[2] + a[3]*a[3];
#pragma unroll
  for (int o = 1; o < 64; o <<= 1) { s += __shfl_xor(s, o, 64); ss += __shfl_xor(ss, o, 64); }
  __shared__ float red[8];
  const int wid = tid >> 6, lane = tid & 63;
  if (lane == 0) { red[wid] = s; red[4 + wid] = ss; }
  __syncthreads();
  s  = red[0] + red[1] + red[2] + red[3];
  ss = red[4] + red[5] + red[6] + red[7];
  float mu  = s * (1.f / DD);
  float var = fmaxf((ss - (float)DD * mu * mu) * (1.f / (DD - 1)), 0.f);
  float inv = g[0] / (1e-6f + sqrtf(var));
  float bb  = be[0];
#pragma unroll
  for (int j = 0; j < 4; ++j) a[j] = (a[j] - mu) * inv + bb;
  *(f32x4*)(xr + tid * 4) = a;
  if (WRITE_BF16) {
    s16x4 o;
#pragma unroll
    for (int j = 0; j < 4; ++j) o[j] = f2bf(a[j]);
    *(s16x4*)(xb + (size_t)row * DD + tid * 4) = o;
  }
}

// ---------------- launcher ----------------
extern "C" void kernel_launch(void* const* d_in, const int* in_sizes, int n_in,
                              void* d_out, int out_size, void* d_ws, size_t ws_size,
                              hipStream_t stream) {
  const float* x    = (const float*)d_in[0];
  const int*   mask = (const int*)d_in[1];
  const float* Wq = (const float*)d_in[2];  const float* bq = (const float*)d_in[3];
  const float* Wk = (const float*)d_in[4];  const float* bk = (const float*)d_in[5];
  const float* Wv = (const float*)d_in[6];  const float* bv = (const float*)d_in[7];
  const float* Wo = (const float*)d_in[8];  const float* bo = (const float*)d_in[9];
  const float* W1 = (const float*)d_in[10]; const float* b1 = (const float*)d_in[11];
  const float* W2 = (const float*)d_in[12]; const float* b2 = (const float*)d_in[13];
  const float* g1 = (const float*)d_in[14]; const float* be1 = (const float*)d_in[15];
  const float* g2 = (const float*)d_in[16]; const float* be2 = (const float*)d_in[17];
  float* out = (float*)d_out;

  char* ws = (char*)d_ws;
  size_t off = 0;
  auto alloc = [&](size_t bytes) -> char* {
    char* p = ws + off; off += (bytes + 255) & ~(size_t)255; return p;
  };
  short* xb  = (short*)alloc((size_t)MT * DD * 2);
  short* wqb = (short*)alloc((size_t)DD * DD * 2);   // wq/wk/wv contiguous => [3072][1024]
  short* wkb = (short*)alloc((size_t)DD * DD * 2);
  short* wvb = (short*)alloc((size_t)DD * DD * 2);
  short* wob = (short*)alloc((size_t)DD * DD * 2);
  short* w1b = (short*)alloc((size_t)DFF * DD * 2);
  short* w2b = (short*)alloc((size_t)DD * DFF * 2);
  short* Qb  = (short*)alloc((size_t)MT * DD * 2);   // Q/K/V contiguous; block reused as F1
  short* Kb  = (short*)alloc((size_t)MT * DD * 2);
  short* Vb  = (short*)alloc((size_t)MT * DD * 2);
  short* Ab  = (short*)alloc((size_t)MT * DD * 2);
  float* x1  = (float*)alloc((size_t)MT * DD * 4);   // first 16 MB doubles as Vt
  short* F1  = Qb;
  short* x1b = xb;
  short* Vt  = (short*)x1;
  (void)wkb; (void)wvb; (void)Kb; (void)Vb;

  cvt_bf16<<<(MT * DD / 8 + 255) / 256, 256, 0, stream>>>(x, xb, MT * DD / 8);
  cvt_bf16<<<(DD * DD / 8 + 255) / 256, 256, 0, stream>>>(Wq, wqb, DD * DD / 8);
  cvt_bf16<<<(DD * DD / 8 + 255) / 256, 256, 0, stream>>>(Wk, wkb, DD * DD / 8);
  cvt_bf16<<<(DD * DD / 8 + 255) / 256, 256, 0, stream>>>(Wv, wvb, DD * DD / 8);
  cvt_bf16<<<(DD * DD / 8 + 255) / 256, 256, 0, stream>>>(Wo, wob, DD * DD / 8);
  cvt_bf16<<<(DFF * DD / 8 + 255) / 256, 256, 0, stream>>>(W1, w1b, DFF * DD / 8);
  cvt_bf16<<<(DD * DFF / 8 + 255) / 256, 256, 0, stream>>>(W2, w2b, DD * DFF / 8);

  // fused QKV: C[8192,3072] = x @ [Wq;Wk;Wv]^T, routed to Qb/Kb/Vb
  gemm_ring<256,0,0,0,1,1><<<dim3((3072/256)*(MT/256)), 512, 0, stream>>>(
      xb, wqb, bq, bk, bv, nullptr, nullptr, Qb, MT, 3072, DD);

  transpose_v<<<dim3(SS/256, 8, BB*HH), 256, 0, stream>>>(Vb, Vt);
  attn_flash2<<<dim3(SS/128, BB*HH), 256, 0, stream>>>(Qb, Kb, Vt, mask, Ab);

  // Wo + residual(x) -> x1 (fp32), then LN1 (+bf16 copy)
  gemm_ring<128,0,1,1,0,0><<<dim3((DD/256)*(MT/128)), 512, 0, stream>>>(
      Ab, wob, bo, bo, bo, x, x1, nullptr, MT, DD, DD);
  layernorm_k<1><<<MT, 256, 0, stream>>>(x1, x1b, g1, be1);

  // FF1 (ReLU, bf16), FF2 (+res x1 -> out fp32), LN2
  gemm_ring<256,1,0,0,1,0><<<dim3((DFF/256)*(MT/256)), 512, 0, stream>>>(
      x1b, w1b, b1, b1, b1, nullptr, nullptr, F1, MT, DFF, DD);
  gemm_ring<128,0,1,1,0,0><<<dim3((DD/256)*(MT/128)), 512, 0, stream>>>(
      F1, w2b, b2, b2, b2, x1, out, nullptr, MT, DD, DFF);
  layernorm_k<0><<<MT, 256, 0, stream>>>(out, nullptr, g2, be2);
}

// Round 5
// 385.972 us; speedup vs baseline: 1.3518x; 1.0383x over previous
//
#include <hip/hip_runtime.h>
#include <stdint.h>

// Problem dims
#define BB 8
#define SS 1024
#define DD 1024
#define HH 16
#define DFF 4096
#define MT (BB*SS)   // 8192 tokens

typedef __attribute__((ext_vector_type(8))) short bf16x8;  // 8 bf16 in 4 VGPRs
typedef __attribute__((ext_vector_type(4))) short s16x4;
typedef __attribute__((ext_vector_type(4))) float f32x4;
typedef __attribute__((ext_vector_type(16))) float f32x16;
typedef unsigned int u32x2 __attribute__((ext_vector_type(2)));

#define LOG2E 1.44269504088896340736f

__device__ __forceinline__ short f2bf(float f) {
  union { float f; uint32_t u; } v; v.f = f;
  uint32_t r = v.u + 0x7FFFu + ((v.u >> 16) & 1u);   // RNE
  return (short)(r >> 16);
}

// async global->LDS, 16B per lane. LDS dest must be wave-uniform base (+lane*16 implicit).
__device__ __forceinline__ void gload_lds16(const void* g, void* l) {
  __builtin_amdgcn_global_load_lds(
      (__attribute__((address_space(1))) uint32_t*)(uintptr_t)g,
      (__attribute__((address_space(3))) uint32_t*)(uint32_t)(uintptr_t)l,
      16, 0, 0);
}

__device__ __forceinline__ uint32_t cvtpk(float lo, float hi) {
  uint32_t r;
  asm("v_cvt_pk_bf16_f32 %0, %1, %2" : "=v"(r) : "v"(lo), "v"(hi));
  return r;
}

__device__ __forceinline__ void swap2(uint32_t a, uint32_t b, uint32_t& x, uint32_t& y) {
#if __has_builtin(__builtin_amdgcn_permlane32_swap)
  u32x2 r = __builtin_amdgcn_permlane32_swap(a, b, false, false);
  x = r.x; y = r.y;
#else
  uint32_t asw = (uint32_t)__shfl_xor((int)a, 32, 64);
  uint32_t bsw = (uint32_t)__shfl_xor((int)b, 32, 64);
  bool h = (threadIdx.x & 32) != 0;
  x = h ? bsw : a;
  y = h ? b : asw;
#endif
}

// ---------------- fp32 -> bf16 convert ----------------
__global__ __launch_bounds__(256) void cvt_bf16(const float* __restrict__ in,
                                                short* __restrict__ out, int n8) {
  int i = blockIdx.x * 256 + threadIdx.x;
  if (i >= n8) return;
  f32x4 a = *(const f32x4*)(in + (size_t)i * 8);
  f32x4 b = *(const f32x4*)(in + (size_t)i * 8 + 4);
  bf16x8 o;
  o[0]=f2bf(a[0]); o[1]=f2bf(a[1]); o[2]=f2bf(a[2]); o[3]=f2bf(a[3]);
  o[4]=f2bf(b[0]); o[5]=f2bf(b[1]); o[6]=f2bf(b[2]); o[7]=f2bf(b[3]);
  *(bf16x8*)(out + (size_t)i * 8) = o;
}

// ---------------- ring-pipelined NT GEMM ----------------
// C[M,N] = A[M,K] @ W[N,K]^T + bias.  BM x 256 tile, BK=32, 512 threads (8 waves, 2Mx4N).
// 3-slot LDS ring, prefetch depth 2, counted vmcnt (never 0 in loop), raw s_barrier.
// For QKV: the Q third (col<1024) is scaled by qscale (folds softmax scale+LOG2E into Q).
template<int BM, int RELU, int RES, int OUTF, int OUTB, int QKV>
__global__ __launch_bounds__(512, 2) void gemm_ring(
    const short* __restrict__ A, const short* __restrict__ W,
    const float* __restrict__ bq, const float* __restrict__ bk,
    const float* __restrict__ bv, const float* __restrict__ res,
    float* __restrict__ outF, short* __restrict__ outB,
    int M, int N, int K, float qscale)
{
  constexpr int AISS   = BM / 128;             // A gload issues per wave per tile
  constexpr int SLOT_A = BM * 32 * 2;          // bytes
  constexpr int SLOT   = SLOT_A + 256 * 32 * 2;
  constexpr int MI     = BM / 32;
  __shared__ __align__(16) char lds[3 * SLOT];

  const int tid = threadIdx.x, lane = tid & 63, wid = tid >> 6;
  const int wm = wid >> 2, wn = wid & 3;
  const int lrow = lane & 15, lk = lane >> 4;

  // XCD-chunked block swizzle (grid % 8 == 0 for all our launches)
  const int nwg = gridDim.x;
  const int cpx = nwg >> 3;
  const int id  = blockIdx.x;
  const int wg  = (id & 7) * cpx + (id >> 3);
  const int gx  = N >> 8;
  const int bx  = wg % gx, by = wg / gx;
  const int row0 = by * BM, col0 = bx * 256;

  // ---- staging lane decomposition ----
  const int lineo = lane >> 3;
  const int rin   = lineo * 2 + ((lane >> 2) & 1);
  const int ksrc  = (lane & 3) ^ (lineo & 3);

  const short* Asrc[AISS];
#pragma unroll
  for (int j = 0; j < AISS; ++j)
    Asrc[j] = A + (size_t)(row0 + (wid * AISS + j) * 16 + rin) * K + ksrc * 8;
  const short* Bsrc[2];
#pragma unroll
  for (int j = 0; j < 2; ++j)
    Bsrc[j] = W + (size_t)(col0 + (wid * 2 + j) * 16 + rin) * K + ksrc * 8;

  const f32x4 z4 = {0.f, 0.f, 0.f, 0.f};
  f32x4 acc[MI][4];
#pragma unroll
  for (int i = 0; i < MI; ++i)
#pragma unroll
    for (int j = 0; j < 4; ++j) acc[i][j] = z4;

  const int NT = K >> 5;

  auto stage = [&](int ts, int s) {
    char* base = lds + s * SLOT;
    int ko = ts * 32;
#pragma unroll
    for (int j = 0; j < AISS; ++j)
      gload_lds16(Asrc[j] + ko, base + (wid * AISS + j) * 1024);
#pragma unroll
    for (int j = 0; j < 2; ++j)
      gload_lds16(Bsrc[j] + ko, base + SLOT_A + (wid * 2 + j) * 1024);
  };

  // prologue: tiles 0,1 -> slots 0,1
  stage(0, 0);
  stage(1, 1);

  const int laneterm = (lrow >> 1) * 128 + (lrow & 1) * 64 + ((lk ^ ((lrow >> 1) & 3)) * 16);

  int sr = 0;
  for (int t = 0; t < NT; ++t) {
    const int sw = (sr == 0) ? 2 : sr - 1;         // (t+2)%3
    const int ts = (t + 2 < NT) ? t + 2 : NT - 1;  // tail clamp (dup stage, harmless)
    stage(ts, sw);
    if (AISS == 2) asm volatile("s_waitcnt vmcnt(8)" ::: "memory");
    else           asm volatile("s_waitcnt vmcnt(6)" ::: "memory");
    __builtin_amdgcn_s_barrier();
    __builtin_amdgcn_sched_barrier(0);

    const char* As = lds + sr * SLOT;
    const char* Bs = As + SLOT_A;
    bf16x8 af[MI], bfr[4];
#pragma unroll
    for (int mi = 0; mi < MI; ++mi)
      af[mi] = *(const bf16x8*)(As + wm * (BM * 32) + mi * 1024 + laneterm);
#pragma unroll
    for (int ni = 0; ni < 4; ++ni)
      bfr[ni] = *(const bf16x8*)(Bs + wn * 4096 + ni * 1024 + laneterm);

    __builtin_amdgcn_s_setprio(1);
#pragma unroll
    for (int mi = 0; mi < MI; ++mi)
#pragma unroll
      for (int ni = 0; ni < 4; ++ni)
        acc[mi][ni] = __builtin_amdgcn_mfma_f32_16x16x32_bf16(af[mi], bfr[ni], acc[mi][ni], 0, 0, 0);
    __builtin_amdgcn_s_setprio(0);

    __builtin_amdgcn_s_barrier();
    sr = (sr == 2) ? 0 : sr + 1;
  }

  // ---- epilogue ----
  const int sel    = QKV ? (col0 >> 10) : 0;
  const float* bias = QKV ? (sel == 0 ? bq : (sel == 1 ? bk : bv)) : bq;
  const int strideN = QKV ? 1024 : N;
  short* outBp = OUTB ? (outB + (QKV ? (size_t)sel * MT * DD : 0)) : outB;
  const float scl = (QKV && sel == 0) ? qscale : 1.f;

#pragma unroll
  for (int mi = 0; mi < MI; ++mi) {
#pragma unroll
    for (int ni = 0; ni < 4; ++ni) {
      int col  = col0 + wn * 64 + ni * 16 + lrow;
      int coll = QKV ? (col & 1023) : col;
      float bvv = bias[coll];
#pragma unroll
      for (int r = 0; r < 4; ++r) {
        int row = row0 + wm * (BM / 2) + mi * 16 + lk * 4 + r;
        float v = acc[mi][ni][r] + bvv;
        if (QKV) v *= scl;
        if (RELU) v = fmaxf(v, 0.f);
        size_t idx = (size_t)row * strideN + coll;
        if (RES)  v += res[idx];
        if (OUTF) outF[idx] = v;
        if (OUTB) outBp[idx] = f2bf(v);
      }
    }
  }
}

// ---------------- V transpose: Vb[b*SS+s][h*64+dk] -> Vt[(bh*64+dk)][s] ----------------
__global__ __launch_bounds__(256) void transpose_v(const short* __restrict__ Vb,
                                                   short* __restrict__ Vt) {
  const int s = blockIdx.x * 256 + threadIdx.x;
  const int u = blockIdx.y;                       // dk group of 8
  const int bh = blockIdx.z, b = bh >> 4, h = bh & 15;
  bf16x8 v = *(const bf16x8*)(Vb + ((size_t)(b * SS + s)) * DD + h * 64 + u * 8);
  size_t ob = ((size_t)bh * 64 + u * 8) * SS + s;
#pragma unroll
  for (int j = 0; j < 8; ++j) Vt[ob + (size_t)j * SS] = v[j];
}

// ---------------- flash attention v3: log2-domain (Q pre-scaled), defer-max,
// double-buffered K/V staging with counted vmcnt ----------------
__global__ __launch_bounds__(256) void attn_flash3(
    const short* __restrict__ Qm, const short* __restrict__ Km,
    const short* __restrict__ Vtg, const int* __restrict__ mask,
    short* __restrict__ Om)
{
  __shared__ short KsB[2 * 64 * 64];  // [buf][key][dk], 16B-unit XOR-swizzled by (key&7)
  __shared__ short VsB[2 * 64 * 64];  // [buf][dk][key], swizzled by (dk&7)
  __shared__ float ma_all[SS];        // additive mask (log2 domain) for all keys
  __shared__ float fb[4 * 32];        // per-wave per-q broadcast slab

  const int tid = threadIdx.x, lane = tid & 63, wid = tid >> 6;
  const int l31 = lane & 31, hi = lane >> 5;
  const int bh = blockIdx.y, b = bh >> 4, h = bh & 15;
  const int q0 = blockIdx.x * 128 + wid * 32;

  // mask prologue: entire row once
  {
    const int* mrow = mask + b * SS;
#pragma unroll
    for (int i = 0; i < 4; ++i) {
      int idx = i * 256 + tid;
      ma_all[idx] = (mrow[idx] == 0) ? -1.442695e9f : 0.f;
    }
  }

  bf16x8 qf[4];
  {
    const short* qrow = Qm + ((size_t)(b * SS + q0 + l31)) * DD + h * 64;
#pragma unroll
    for (int t = 0; t < 4; ++t) qf[t] = *(const bf16x8*)(qrow + t * 16 + hi * 8);
  }

  f32x16 acc0, acc1;
#pragma unroll
  for (int i = 0; i < 16; ++i) { acc0[i] = 0.f; acc1[i] = 0.f; }
  float m_r = -3e38f, l_r = 0.f;

  const int srow = tid >> 3;
  const int su = tid & 7;

  auto stageKV = [&](int kt2, int bi) {
#pragma unroll
    for (int i = 0; i < 2; ++i) {
      int r = i * 32 + srow;
      int uu = su ^ (r & 7);
      gload_lds16(Km + ((size_t)(b * SS + kt2 + r)) * DD + h * 64 + uu * 8,
                  KsB + bi * 4096 + (i * 256 + wid * 64) * 8);
      gload_lds16(Vtg + ((size_t)(bh * 64 + r)) * SS + kt2 + uu * 8,
                  VsB + bi * 4096 + (i * 256 + wid * 64) * 8);
    }
  };

  __syncthreads();           // mask writes visible; all prologue vmem drained
  stageKV(0, 0);

  for (int t = 0; t < 16; ++t) {
    if (t < 15) {
      stageKV((t + 1) << 6, (t + 1) & 1);
      asm volatile("s_waitcnt vmcnt(4)" ::: "memory");
    } else {
      asm volatile("s_waitcnt vmcnt(0)" ::: "memory");
    }
    __builtin_amdgcn_s_barrier();
    __builtin_amdgcn_sched_barrier(0);

    const short* Ks = KsB + (t & 1) * 4096;
    const short* Vs = VsB + (t & 1) * 4096;

    // S^T[key][q] = K·Q^T (scores already in log2 domain; Q pre-scaled)
    f32x16 s0, s1;
#pragma unroll
    for (int i = 0; i < 16; ++i) { s0[i] = 0.f; s1[i] = 0.f; }
#pragma unroll
    for (int t4 = 0; t4 < 4; ++t4) {
      int u = (t4 * 2 + hi) ^ (l31 & 7);
      bf16x8 k0 = *(const bf16x8*)(Ks + l31 * 64 + u * 8);
      bf16x8 k1 = *(const bf16x8*)(Ks + (32 + l31) * 64 + u * 8);
      s0 = __builtin_amdgcn_mfma_f32_32x32x16_bf16(k0, qf[t4], s0, 0, 0, 0);
      s1 = __builtin_amdgcn_mfma_f32_32x32x16_bf16(k1, qf[t4], s1, 0, 0, 0);
    }

    // mask add + max
    const float* map = ma_all + (t << 6);
    float p0[16], p1[16];
    float mx = -3e38f;
#pragma unroll
    for (int g = 0; g < 4; ++g) {
      f32x4 a0 = *(const f32x4*)(map + g * 8 + hi * 4);
      f32x4 a1 = *(const f32x4*)(map + 32 + g * 8 + hi * 4);
#pragma unroll
      for (int j = 0; j < 4; ++j) {
        float v0 = s0[g * 4 + j] + a0[j];
        float v1 = s1[g * 4 + j] + a1[j];
        p0[g * 4 + j] = v0; p1[g * 4 + j] = v1;
        mx = fmaxf(mx, fmaxf(v0, v1));
      }
    }
    mx = fmaxf(mx, __shfl_xor(mx, 32, 64));

    // defer-max: rescale only when the max actually grows beyond threshold
    if (!__all(mx <= m_r + 8.f)) {
      float mn  = fmaxf(m_r, mx);
      float fac = exp2f(m_r - mn);
      m_r = mn;
      l_r *= fac;
      fb[wid * 32 + l31] = fac;
#pragma unroll
      for (int g = 0; g < 4; ++g) {
        f32x4 fv = *(const f32x4*)(fb + wid * 32 + g * 8 + hi * 4);
#pragma unroll
        for (int j = 0; j < 4; ++j) { acc0[g * 4 + j] *= fv[j]; acc1[g * 4 + j] *= fv[j]; }
      }
    }

    float rs = 0.f;
#pragma unroll
    for (int r = 0; r < 16; ++r) {
      p0[r] = exp2f(p0[r] - m_r);
      p1[r] = exp2f(p1[r] - m_r);
      rs += p0[r] + p1[r];
    }
    rs += __shfl_xor(rs, 32, 64);
    l_r += rs;

    // P -> bf16 A-fragments in-register: 16 cvt_pk + 8 permlane32_swap
    uint32_t w0[8], w1[8];
#pragma unroll
    for (int m = 0; m < 8; ++m) {
      w0[m] = cvtpk(p0[2 * m], p0[2 * m + 1]);
      w1[m] = cvtpk(p1[2 * m], p1[2 * m + 1]);
    }
    uint32_t pa[4][4];
    swap2(w0[0], w0[2], pa[0][0], pa[0][2]);
    swap2(w0[1], w0[3], pa[0][1], pa[0][3]);
    swap2(w0[4], w0[6], pa[1][0], pa[1][2]);
    swap2(w0[5], w0[7], pa[1][1], pa[1][3]);
    swap2(w1[0], w1[2], pa[2][0], pa[2][2]);
    swap2(w1[1], w1[3], pa[2][1], pa[2][3]);
    swap2(w1[4], w1[6], pa[3][0], pa[3][2]);
    swap2(w1[5], w1[7], pa[3][1], pa[3][3]);

#pragma unroll
    for (int kc = 0; kc < 4; ++kc) {
      union { uint32_t w[4]; bf16x8 v; } pu;
      pu.w[0] = pa[kc][0]; pu.w[1] = pa[kc][1]; pu.w[2] = pa[kc][2]; pu.w[3] = pa[kc][3];
      int u = (kc * 2 + hi) ^ (l31 & 7);
      bf16x8 v0 = *(const bf16x8*)(Vs + l31 * 64 + u * 8);
      bf16x8 v1 = *(const bf16x8*)(Vs + (32 + l31) * 64 + u * 8);
      acc0 = __builtin_amdgcn_mfma_f32_32x32x16_bf16(pu.v, v0, acc0, 0, 0, 0);
      acc1 = __builtin_amdgcn_mfma_f32_32x32x16_bf16(pu.v, v1, acc1, 0, 0, 0);
    }

    __builtin_amdgcn_s_barrier();
  }

  fb[wid * 32 + l31] = 1.f / l_r;
#pragma unroll
  for (int g = 0; g < 4; ++g) {
    f32x4 rv = *(const f32x4*)(fb + wid * 32 + g * 8 + hi * 4);
#pragma unroll
    for (int j = 0; j < 4; ++j) {
      int q = q0 + g * 8 + hi * 4 + j;
      size_t base = ((size_t)(b * SS + q)) * DD + h * 64 + l31;
      Om[base]      = f2bf(acc0[g * 4 + j] * rv[j]);
      Om[base + 32] = f2bf(acc1[g * 4 + j] * rv[j]);
    }
  }
}

// ---------------- LayerNorm (ddof=1, eps added to sigma) ----------------
template<int WRITE_BF16>
__global__ __launch_bounds__(256) void layernorm_k(
    float* __restrict__ x, short* __restrict__ xb,
    const float* __restrict__ g, const float* __restrict__ be)
{
  const int row = blockIdx.x, tid = threadIdx.x;
  float* xr = x + (size_t)row * DD;
  f32x4 a = *(const f32x4*)(xr + tid * 4);
  float s  = a[0] + a[1] + a[2] + a[3];
  float ss = a[0]*a[0] + a[1]*a[1] + a[2]*a[2] + a[3]*a[3];
#pragma unroll
  for (int o = 1; o < 64; o <<= 1) { s += __shfl_xor(s, o, 64); ss += __shfl_xor(ss, o, 64); }
  __shared__ float red[8];
  const int wid = tid >> 6, lane = tid & 63;
  if (lane == 0) { red[wid] = s; red[4 + wid] = ss; }
  __syncthreads();
  s  = red[0] + red[1] + red[2] + red[3];
  ss = red[4] + red[5] + red[6] + red[7];
  float mu  = s * (1.f / DD);
  float var = fmaxf((ss - (float)DD * mu * mu) * (1.f / (DD - 1)), 0.f);
  float inv = g[0] / (1e-6f + sqrtf(var));
  float bb  = be[0];
#pragma unroll
  for (int j = 0; j < 4; ++j) a[j] = (a[j] - mu) * inv + bb;
  *(f32x4*)(xr + tid * 4) = a;
  if (WRITE_BF16) {
    s16x4 o;
#pragma unroll
    for (int j = 0; j < 4; ++j) o[j] = f2bf(a[j]);
    *(s16x4*)(xb + (size_t)row * DD + tid * 4) = o;
  }
}

// ---------------- launcher ----------------
extern "C" void kernel_launch(void* const* d_in, const int* in_sizes, int n_in,
                              void* d_out, int out_size, void* d_ws, size_t ws_size,
                              hipStream_t stream) {
  const float* x    = (const float*)d_in[0];
  const int*   mask = (const int*)d_in[1];
  const float* Wq = (const float*)d_in[2];  const float* bq = (const float*)d_in[3];
  const float* Wk = (const float*)d_in[4];  const float* bk = (const float*)d_in[5];
  const float* Wv = (const float*)d_in[6];  const float* bv = (const float*)d_in[7];
  const float* Wo = (const float*)d_in[8];  const float* bo = (const float*)d_in[9];
  const float* W1 = (const float*)d_in[10]; const float* b1 = (const float*)d_in[11];
  const float* W2 = (const float*)d_in[12]; const float* b2 = (const float*)d_in[13];
  const float* g1 = (const float*)d_in[14]; const float* be1 = (const float*)d_in[15];
  const float* g2 = (const float*)d_in[16]; const float* be2 = (const float*)d_in[17];
  float* out = (float*)d_out;

  char* ws = (char*)d_ws;
  size_t off = 0;
  auto alloc = [&](size_t bytes) -> char* {
    char* p = ws + off; off += (bytes + 255) & ~(size_t)255; return p;
  };
  short* xb  = (short*)alloc((size_t)MT * DD * 2);
  short* wqb = (short*)alloc((size_t)DD * DD * 2);   // wq/wk/wv contiguous => [3072][1024]
  short* wkb = (short*)alloc((size_t)DD * DD * 2);
  short* wvb = (short*)alloc((size_t)DD * DD * 2);
  short* wob = (short*)alloc((size_t)DD * DD * 2);
  short* w1b = (short*)alloc((size_t)DFF * DD * 2);
  short* w2b = (short*)alloc((size_t)DD * DFF * 2);
  short* Qb  = (short*)alloc((size_t)MT * DD * 2);   // Q/K/V contiguous; block reused as F1
  short* Kb  = (short*)alloc((size_t)MT * DD * 2);
  short* Vb  = (short*)alloc((size_t)MT * DD * 2);
  short* Ab  = (short*)alloc((size_t)MT * DD * 2);
  float* x1  = (float*)alloc((size_t)MT * DD * 4);   // first 16 MB doubles as Vt
  short* F1  = Qb;
  short* x1b = xb;
  short* Vt  = (short*)x1;
  (void)wkb; (void)wvb; (void)Kb; (void)Vb;

  const float qscale = 0.125f * LOG2E;   // softmax scale + log2-domain fold

  cvt_bf16<<<(MT * DD / 8 + 255) / 256, 256, 0, stream>>>(x, xb, MT * DD / 8);
  cvt_bf16<<<(DD * DD / 8 + 255) / 256, 256, 0, stream>>>(Wq, wqb, DD * DD / 8);
  cvt_bf16<<<(DD * DD / 8 + 255) / 256, 256, 0, stream>>>(Wk, wkb, DD * DD / 8);
  cvt_bf16<<<(DD * DD / 8 + 255) / 256, 256, 0, stream>>>(Wv, wvb, DD * DD / 8);
  cvt_bf16<<<(DD * DD / 8 + 255) / 256, 256, 0, stream>>>(Wo, wob, DD * DD / 8);
  cvt_bf16<<<(DFF * DD / 8 + 255) / 256, 256, 0, stream>>>(W1, w1b, DFF * DD / 8);
  cvt_bf16<<<(DD * DFF / 8 + 255) / 256, 256, 0, stream>>>(W2, w2b, DD * DFF / 8);

  // fused QKV: C[8192,3072] = x @ [Wq;Wk;Wv]^T, routed to Qb/Kb/Vb (Q pre-scaled)
  gemm_ring<128,0,0,0,1,1><<<dim3((3072/256)*(MT/128)), 512, 0, stream>>>(
      xb, wqb, bq, bk, bv, nullptr, nullptr, Qb, MT, 3072, DD, qscale);

  transpose_v<<<dim3(SS/256, 8, BB*HH), 256, 0, stream>>>(Vb, Vt);
  attn_flash3<<<dim3(SS/128, BB*HH), 256, 0, stream>>>(Qb, Kb, Vt, mask, Ab);

  // Wo + residual(x) -> x1 (fp32), then LN1 (+bf16 copy)
  gemm_ring<128,0,1,1,0,0><<<dim3((DD/256)*(MT/128)), 512, 0, stream>>>(
      Ab, wob, bo, bo, bo, x, x1, nullptr, MT, DD, DD, 1.f);
  layernorm_k<1><<<MT, 256, 0, stream>>>(x1, x1b, g1, be1);

  // FF1 (ReLU, bf16), FF2 (+res x1 -> out fp32), LN2
  gemm_ring<128,1,0,0,1,0><<<dim3((DFF/256)*(MT/128)), 512, 0, stream>>>(
      x1b, w1b, b1, b1, b1, nullptr, nullptr, F1, MT, DFF, DD, 1.f);
  gemm_ring<128,0,1,1,0,0><<<dim3((DD/256)*(MT/128)), 512, 0, stream>>>(
      F1, w2b, b2, b2, b2, x1, out, nullptr, MT, DD, DFF, 1.f);
  layernorm_k<0><<<MT, 256, 0, stream>>>(out, nullptr, g2, be2);
}